// Round 3
// baseline (317.079 us; speedup 1.0000x reference)
//
#include <hip/hip_runtime.h>
#include <math.h>

#define B_TOTAL 16384
#define T_STEPS 20
#define NGRP    1024            // B_TOTAL/16 batch groups per sensor

typedef __attribute__((ext_vector_type(8))) __bf16 bf16x8;
typedef __attribute__((ext_vector_type(4))) float f32x4;

// ---------------------------------------------------------------------------
// pack top-16-bits of two floats into one u32: low16 = a's, high16 = b's
__device__ __forceinline__ unsigned pack_hi16(unsigned a, unsigned b) {
#if __has_builtin(__builtin_amdgcn_perm)
    return __builtin_amdgcn_perm(b, a, 0x07060302u);
#else
    return (a >> 16) | (b & 0xFFFF0000u);
#endif
}

__device__ __forceinline__ __bf16 bf16_bits(unsigned short s) {
    __bf16 r; __builtin_memcpy(&r, &s, 2); return r;
}
// Truncation-based Dekker split (unchanged numerics).
__device__ __forceinline__ void split_trunc(float x, __bf16& hi, __bf16& lo) {
    unsigned u = __float_as_uint(x);
    hi = bf16_bits((unsigned short)(u >> 16));
    float l = x - __uint_as_float(u & 0xFFFF0000u);
    lo = bf16_bits((unsigned short)(__float_as_uint(l) >> 16));
}

// Fused LSTM cell activation (5 exp + 2 rcp; algebraically = sigmoid/tanh form):
//   c' = [c*(1+A)(1+C) + (C-1)(1+B)] / [(1+A)(1+B)(1+C)]   A=e^-xi B=e^-xf C=e^2xg
//   h  = (E-1) / ((1+D)(1+E))                              D=e^-xo E=e^2c'
__device__ __forceinline__ float lstm_act(f32x4 a, float& c) {
    float eA = __expf(-a[0]);
    float eB = __expf(-a[1]);
    float eC = __expf(2.0f * a[2]);
    float aA = 1.0f + eA, aB = 1.0f + eB, aC = 1.0f + eC;
    float pAC = aA * aC;
    float r1  = __builtin_amdgcn_rcpf(pAC * aB);
    c = fmaf(c, pAC, (eC - 1.0f) * aB) * r1;
    float eD = __expf(-a[3]);
    float eE = __expf(2.0f * c);
    float r2 = __builtin_amdgcn_rcpf((1.0f + eD) * (1.0f + eE));
    return (eE - 1.0f) * r2;
}

// ---------------------------------------------------------------------------
// Fused 5-layer LSTM via bf16 MFMA, hi/lo compensated.
//
// R3: 2 waves / 128 threads per block; each wave owns 16 hidden units as
// 4 M-tiles; each thread owns 4 CONSECUTIVE units u = w*16+quad*4+{0..3}.
//  * LDS read traffic: each wave reads the slab pair once for 4 tiles
//    (24 MFMAs per 4 b128 reads) -> 8 KB/group-step, 4x less than R2.
//  * 4 independent MFMA dep-chains per thread -> matrix pipe throughput-
//    bound instead of latency-serial.
//  * h-store: 4 consecutive units pack into ONE ds_write_b64 (hi) + one
//    (lo) via v_perm -- 2 write instrs/thread-step.
//  * Occupancy 8 waves/CU (2/SIMD) -- intentionally low; kernel is
//    VALU-issue-bound and per-wave ILP covers latency.
// LDS physical layout identical to R2 (same swizzle family), so the
// epilogue dump, w1_prep and fc_mfma are unchanged.
__global__ __launch_bounds__(128, 2)
void lstm5_mfma(const float* __restrict__ accel, const float* __restrict__ gyro,
                const float* __restrict__ aWih0, const float* __restrict__ aWihR,
                const float* __restrict__ aWhh,  const float* __restrict__ aBih,
                const float* __restrict__ aBhh,
                const float* __restrict__ gWih0, const float* __restrict__ gWihR,
                const float* __restrict__ gWhh,  const float* __restrict__ gBih,
                const float* __restrict__ gBhh,
                __bf16* __restrict__ Xhi, __bf16* __restrict__ Xlo) {
    const int tid  = threadIdx.x;
    const int w    = tid >> 6;        // wave 0..1
    const int lane = tid & 63;
    const int e    = lane & 15;       // batch col within group
    const int quad = lane >> 4;       // 0..3
    const int sensor = blockIdx.y;
    const int bbase  = blockIdx.x * 16;

    const float* xin  = sensor ? gyro  : accel;
    const float* Wih0 = sensor ? gWih0 : aWih0;
    const float* WihR = sensor ? gWihR : aWihR;
    const float* Whh  = sensor ? gWhh  : aWhh;
    const float* Bih  = sensor ? gBih  : aBih;
    const float* Bhh  = sensor ? gBhh  : aBhh;

    __shared__ __align__(16) unsigned shi[20 * 256];   // bf16 pairs (20 KB)
    __shared__ __align__(16) unsigned slo[20 * 256];
    const __bf16* sh16 = (const __bf16*)shi;
    const __bf16* sl16 = (const __bf16*)slo;

    const int swz = (e >> 1) & 3;
    // write base (u32 units in a t-slab): words {base, base+1} = units
    // w*16+quad*4 .. +3;  physical p = k ^ (swz<<2)
    const int wr_base = e * 16 + ((w * 8 + quad * 2) ^ (swz << 2));
    // read base (bf16 units): 8 bf16 = units quad*8..+7 for col e (as R2)
    const int rb_base = e * 32 + ((quad ^ swz) << 3);

    // A-row mapping for tile j: gate=(e&3), unit = w*16 + (e>>2)*4 + j
    const int orow0 = (e & 3) * 32 + w * 16 + (e >> 2) * 4;   // + j

    bf16x8 wih_h[4], wih_l[4], whh_h[4], whh_l[4];
    f32x4  biasv[4];
    float  cst[4];

// A-frag natural column order: slot jj holds W[row][quad*8 + jj]
#define LOAD_FRAG(Wsrc, j, fh, fl)                                  \
    {                                                               \
        const float* p_ = (Wsrc) + (orow0 + (j)) * 32 + quad * 8;   \
        _Pragma("unroll")                                           \
        for (int jj = 0; jj < 8; ++jj) {                            \
            __bf16 h_, l_;                                          \
            split_trunc(p_[jj], h_, l_);                            \
            (fh)[(j)][jj] = h_;  (fl)[(j)][jj] = l_;                \
        }                                                           \
    }

#define LOAD_BIAS(l)                                                         \
    {                                                                        \
        _Pragma("unroll")                                                    \
        for (int j = 0; j < 4; ++j) {                                        \
            int u_ = w * 16 + quad * 4 + j;                                  \
            _Pragma("unroll")                                                \
            for (int r = 0; r < 4; ++r)                                      \
                biasv[j][r] = Bih[(l) * 128 + r * 32 + u_] +                 \
                              Bhh[(l) * 128 + r * 32 + u_];                  \
        }                                                                    \
    }

// activation + packed b64 store of 4 consecutive-unit h values
#define ACT_STORE(t)                                                         \
    {                                                                        \
        float h0 = lstm_act(acc[0], cst[0]);                                 \
        float h1 = lstm_act(acc[1], cst[1]);                                 \
        float h2 = lstm_act(acc[2], cst[2]);                                 \
        float h3 = lstm_act(acc[3], cst[3]);                                 \
        unsigned b0 = __float_as_uint(h0), b1 = __float_as_uint(h1);         \
        unsigned b2 = __float_as_uint(h2), b3 = __float_as_uint(h3);         \
        unsigned hw0 = pack_hi16(b0, b1), hw1 = pack_hi16(b2, b3);           \
        float l0 = h0 - __uint_as_float(b0 & 0xFFFF0000u);                   \
        float l1 = h1 - __uint_as_float(b1 & 0xFFFF0000u);                   \
        float l2 = h2 - __uint_as_float(b2 & 0xFFFF0000u);                   \
        float l3 = h3 - __uint_as_float(b3 & 0xFFFF0000u);                   \
        unsigned lw0 = pack_hi16(__float_as_uint(l0), __float_as_uint(l1));  \
        unsigned lw1 = pack_hi16(__float_as_uint(l2), __float_as_uint(l3));  \
        __syncthreads();  /* all waves done reading shi/slo[t] */            \
        *(uint2*)(shi + (t) * 256 + wr_base) = make_uint2(hw0, hw1);         \
        *(uint2*)(slo + (t) * 256 + wr_base) = make_uint2(lw0, lw1);         \
        __syncthreads();  /* writes visible before next step's reads */      \
    }

    // ================= layer 0 (ih is K=3, done in VALU) =================
    {
#pragma unroll
        for (int j = 0; j < 4; ++j) LOAD_FRAG(Whh, j, whh_h, whh_l);
        LOAD_BIAS(0);
#pragma unroll
        for (int j = 0; j < 4; ++j) cst[j] = 0.f;

        float w0reg[4][4][3];
#pragma unroll
        for (int j = 0; j < 4; ++j) {
            int u_ = w * 16 + quad * 4 + j;
#pragma unroll
            for (int r = 0; r < 4; ++r)
#pragma unroll
                for (int k = 0; k < 3; ++k)
                    w0reg[j][r][k] = Wih0[(r * 32 + u_) * 3 + k];
        }
        const float* xrow = xin + (size_t)(bbase + e) * (T_STEPS * 3);

        for (int t = 0; t < T_STEPS; ++t) {
            float x0 = xrow[t * 3 + 0];
            float x1 = xrow[t * 3 + 1];
            float x2 = xrow[t * 3 + 2];
            f32x4 acc[4];
#pragma unroll
            for (int j = 0; j < 4; ++j) {
#pragma unroll
                for (int r = 0; r < 4; ++r)
                    acc[j][r] = fmaf(w0reg[j][r][0], x0,
                                fmaf(w0reg[j][r][1], x1,
                                fmaf(w0reg[j][r][2], x2, biasv[j][r])));
            }
            if (t > 0) {
                int rb = (t - 1) * 512 + rb_base;
                bf16x8 bh = *(const bf16x8*)(sh16 + rb);
                bf16x8 bl = *(const bf16x8*)(sl16 + rb);
#pragma unroll
                for (int j = 0; j < 4; ++j) {
                    acc[j] = __builtin_amdgcn_mfma_f32_16x16x32_bf16(whh_h[j], bh, acc[j], 0, 0, 0);
                    acc[j] = __builtin_amdgcn_mfma_f32_16x16x32_bf16(whh_h[j], bl, acc[j], 0, 0, 0);
                    acc[j] = __builtin_amdgcn_mfma_f32_16x16x32_bf16(whh_l[j], bh, acc[j], 0, 0, 0);
                }
            }
            ACT_STORE(t);
        }
    }

    // ================= layers 1..4 (both projections via MFMA) ===========
    for (int l = 1; l < 5; ++l) {
        const float* Wi = WihR + (l - 1) * 4096;
        const float* Wh = Whh + l * 4096;
#pragma unroll
        for (int j = 0; j < 4; ++j) {
            LOAD_FRAG(Wi, j, wih_h, wih_l);
            LOAD_FRAG(Wh, j, whh_h, whh_l);
        }
        LOAD_BIAS(l);
#pragma unroll
        for (int j = 0; j < 4; ++j) cst[j] = 0.f;

        for (int t = 0; t < T_STEPS; ++t) {
            const int rb1 = t * 512 + rb_base;
            bf16x8 bh1 = *(const bf16x8*)(sh16 + rb1);
            bf16x8 bl1 = *(const bf16x8*)(sl16 + rb1);
            f32x4 acc[4];
            // ih: x = h_{l-1}(t); bias rides in as C of first MFMA
#pragma unroll
            for (int j = 0; j < 4; ++j) {
                acc[j] = __builtin_amdgcn_mfma_f32_16x16x32_bf16(wih_h[j], bh1, biasv[j], 0, 0, 0);
                acc[j] = __builtin_amdgcn_mfma_f32_16x16x32_bf16(wih_h[j], bl1, acc[j], 0, 0, 0);
                acc[j] = __builtin_amdgcn_mfma_f32_16x16x32_bf16(wih_l[j], bh1, acc[j], 0, 0, 0);
            }
            if (t > 0) {
                const int rb0 = rb1 - 512;
                bf16x8 bh = *(const bf16x8*)(sh16 + rb0);
                bf16x8 bl = *(const bf16x8*)(sl16 + rb0);
#pragma unroll
                for (int j = 0; j < 4; ++j) {
                    acc[j] = __builtin_amdgcn_mfma_f32_16x16x32_bf16(whh_h[j], bh, acc[j], 0, 0, 0);
                    acc[j] = __builtin_amdgcn_mfma_f32_16x16x32_bf16(whh_h[j], bl, acc[j], 0, 0, 0);
                    acc[j] = __builtin_amdgcn_mfma_f32_16x16x32_bf16(whh_l[j], bh, acc[j], 0, 0, 0);
                }
            }
            ACT_STORE(t);
        }
    }
    __syncthreads();

    // ---- epilogue: raw copy of (physical) frag-layout hi/lo to global ----
    {
        size_t base = ((size_t)(sensor * NGRP + blockIdx.x)) * (20 * 512);
        float4* dh = (float4*)(Xhi + base);
        float4* dl = (float4*)(Xlo + base);
        const float4* sh = (const float4*)shi;
        const float4* sl = (const float4*)slo;
        for (int i = tid; i < 1280; i += 128) { dh[i] = sh[i]; dl[i] = sl[i]; }
    }
#undef LOAD_FRAG
#undef LOAD_BIAS
#undef ACT_STORE
}

// ---------------------------------------------------------------------------
// fc1_w [128][1280] -> MFMA A-frag hi/lo arrays: [mt 0..7][ks 0..39][lane][8]
// Natural column order (matches natural-unit B layout). Unchanged from R2.
__global__ void w1_prep(const float* __restrict__ w1,
                        __bf16* __restrict__ w1ah, __bf16* __restrict__ w1al) {
    int t = blockIdx.x * blockDim.x + threadIdx.x;     // 8*40*64 = 20480
    if (t >= 20480) return;
    int lane = t & 63;
    int ks   = (t >> 6) % 40;
    int mt   = t / (64 * 40);
    int row  = mt * 16 + (lane & 15);
    int col0 = ks * 32 + (lane >> 4) * 8;
    const float* src = w1 + row * 1280 + col0;
#pragma unroll
    for (int j = 0; j < 8; ++j) {
        __bf16 h_, l_;
        split_trunc(src[j], h_, l_);
        w1ah[t * 8 + j] = h_;
        w1al[t * 8 + j] = l_;
    }
}

// ---------------------------------------------------------------------------
// Fused fc1+ReLU+fc2, K-split: block = 256 thr / 4 waves owns 16 batch cols;
// wave wv handles ks = wv*10 .. wv*10+9 (of 40) for ALL 8 m-tiles; C-partials
// reduced through LDS. Unchanged from R2.
__global__ __launch_bounds__(256, 4)
void fc_mfma(const __bf16* __restrict__ Xhi, const __bf16* __restrict__ Xlo,
             const __bf16* __restrict__ w1ah, const __bf16* __restrict__ w1al,
             const float* __restrict__ fc1_b, const float* __restrict__ fc2_w,
             const float* __restrict__ fc2_b, float* __restrict__ out) {
    const int tid  = threadIdx.x;
    const int wv   = tid >> 6;       // ks-quarter
    const int lane = tid & 63;
    const int e    = lane & 15;
    const int quad = lane >> 4;
    const int g    = blockIdx.x;     // batch group (16 cols)

    // match lstm5's physical layout: units quad*8..+7 for col e
    const int lnoff = e * 32 + ((quad ^ ((e >> 1) & 3)) << 3);

    __shared__ __align__(16) f32x4 sacc[4][8][64];   // 32 KB C-partials
    __shared__ float sred[4][16][5];

    f32x4 acc[8];
#pragma unroll
    for (int m = 0; m < 8; ++m) acc[m] = (f32x4){0.f, 0.f, 0.f, 0.f};

    for (int kk = 0; kk < 10; ++kk) {
        int ks = wv * 10 + kk;                 // 0..39
        int sensor = ks / 20, t = ks % 20;     // col = sensor*640 + t*32 + u
        size_t bb = ((size_t)(sensor * NGRP + g)) * (20 * 512) + t * 512 + lnoff;
        bf16x8 bh = *(const bf16x8*)(Xhi + bb);
        bf16x8 bl = *(const bf16x8*)(Xlo + bb);
#pragma unroll
        for (int m = 0; m < 8; ++m) {
            const __bf16* ap = w1ah + ((size_t)((m * 40 + ks) * 64 + lane)) * 8;
            const __bf16* al = w1al + ((size_t)((m * 40 + ks) * 64 + lane)) * 8;
            bf16x8 ah = *(const bf16x8*)ap;
            bf16x8 av = *(const bf16x8*)al;
            acc[m] = __builtin_amdgcn_mfma_f32_16x16x32_bf16(ah, bh, acc[m], 0, 0, 0);
            acc[m] = __builtin_amdgcn_mfma_f32_16x16x32_bf16(ah, bl, acc[m], 0, 0, 0);
            acc[m] = __builtin_amdgcn_mfma_f32_16x16x32_bf16(av, bh, acc[m], 0, 0, 0);
        }
    }
#pragma unroll
    for (int m = 0; m < 8; ++m) sacc[wv][m][lane] = acc[m];
    __syncthreads();

    // phase 2: wave wv reduces m-tiles {2wv, 2wv+1}: sum K-partials, bias,
    // ReLU, fc2 partial over its rows; butterfly over quad bits.
    float p[5] = {0.f, 0.f, 0.f, 0.f, 0.f};
#pragma unroll
    for (int mm = 0; mm < 2; ++mm) {
        int mt = wv * 2 + mm;
        f32x4 z = sacc[0][mt][lane];
#pragma unroll
        for (int k = 1; k < 4; ++k) {
            f32x4 zz = sacc[k][mt][lane];
#pragma unroll
            for (int r = 0; r < 4; ++r) z[r] += zz[r];
        }
#pragma unroll
        for (int r = 0; r < 4; ++r) {
            int row = mt * 16 + quad * 4 + r;      // C row = quad*4 + reg
            float v = fmaxf(z[r] + fc1_b[row], 0.f);
#pragma unroll
            for (int n = 0; n < 5; ++n) p[n] = fmaf(v, fc2_w[n * 128 + row], p[n]);
        }
    }
#pragma unroll
    for (int n = 0; n < 5; ++n) {
        p[n] += __shfl_xor(p[n], 16, 64);
        p[n] += __shfl_xor(p[n], 32, 64);
    }
    if (quad == 0) {
#pragma unroll
        for (int n = 0; n < 5; ++n) sred[wv][e][n] = p[n];
    }
    __syncthreads();
    if (tid < 80) {
        int col = tid / 5, n = tid - col * 5;
        out[(size_t)(g * 16 + col) * 5 + n] =
            sred[0][col][n] + sred[1][col][n] + sred[2][col][n] + sred[3][col][n] + fc2_b[n];
    }
}

// ---------------------------------------------------------------------------
extern "C" void kernel_launch(void* const* d_in, const int* in_sizes, int n_in,
                              void* d_out, int out_size, void* d_ws, size_t ws_size,
                              hipStream_t stream) {
    const float* accel  = (const float*)d_in[0];
    const float* gyro   = (const float*)d_in[1];
    const float* aWih0  = (const float*)d_in[2];
    const float* aWihR  = (const float*)d_in[3];
    const float* aWhh   = (const float*)d_in[4];
    const float* aBih   = (const float*)d_in[5];
    const float* aBhh   = (const float*)d_in[6];
    const float* gWih0  = (const float*)d_in[7];
    const float* gWihR  = (const float*)d_in[8];
    const float* gWhh   = (const float*)d_in[9];
    const float* gBih   = (const float*)d_in[10];
    const float* gBhh   = (const float*)d_in[11];
    const float* fc1_w  = (const float*)d_in[12];
    const float* fc1_b  = (const float*)d_in[13];
    const float* fc2_w  = (const float*)d_in[14];
    const float* fc2_b  = (const float*)d_in[15];
    float* out = (float*)d_out;

    const size_t XN = (size_t)2 * NGRP * 20 * 512;    // 20,971,520 bf16 each
    __bf16* Xhi  = (__bf16*)d_ws;
    __bf16* Xlo  = Xhi + XN;
    __bf16* W1ah = Xlo + XN;                          // 163,840 bf16 each
    __bf16* W1al = W1ah + 163840;

    hipLaunchKernelGGL(w1_prep, dim3(80), dim3(256), 0, stream, fc1_w, W1ah, W1al);

    hipLaunchKernelGGL(lstm5_mfma, dim3(NGRP, 2), dim3(128), 0, stream,
                       accel, gyro, aWih0, aWihR, aWhh, aBih, aBhh,
                       gWih0, gWihR, gWhh, gBih, gBhh, Xhi, Xlo);

    hipLaunchKernelGGL(fc_mfma, dim3(NGRP), dim3(256), 0, stream,
                       Xhi, Xlo, W1ah, W1al, fc1_b, fc2_w, fc2_b, out);
}

// Round 4
// 309.065 us; speedup vs baseline: 1.0259x; 1.0259x over previous
//
#include <hip/hip_runtime.h>
#include <math.h>

#define B_TOTAL 16384
#define T_STEPS 20
#define NGRP    1024            // B_TOTAL/16 batch groups per sensor
#define NSLAB   21              // rotating h-slabs (20 + 1 spare for layer shift)

typedef __attribute__((ext_vector_type(8))) __bf16 bf16x8;
typedef __attribute__((ext_vector_type(4))) float f32x4;

// ---------------------------------------------------------------------------
__device__ __forceinline__ __bf16 bf16_bits(unsigned short s) {
    __bf16 r; __builtin_memcpy(&r, &s, 2); return r;
}
// Truncation-based Dekker split (unchanged numerics).
__device__ __forceinline__ void split_trunc(float x, __bf16& hi, __bf16& lo) {
    unsigned u = __float_as_uint(x);
    hi = bf16_bits((unsigned short)(u >> 16));
    float l = x - __uint_as_float(u & 0xFFFF0000u);
    lo = bf16_bits((unsigned short)(__float_as_uint(l) >> 16));
}

// Fused LSTM cell activation (5 exp + 2 rcp; algebraically = sigmoid/tanh form):
//   c' = [c*(1+A)(1+C) + (C-1)(1+B)] / [(1+A)(1+B)(1+C)]   A=e^-xi B=e^-xf C=e^2xg
//   h  = (E-1) / ((1+D)(1+E))                              D=e^-xo E=e^2c'
__device__ __forceinline__ float lstm_act(f32x4 a, float& c) {
    float eA = __expf(-a[0]);
    float eB = __expf(-a[1]);
    float eC = __expf(2.0f * a[2]);
    float aA = 1.0f + eA, aB = 1.0f + eB, aC = 1.0f + eC;
    float pAC = aA * aC;
    float r1  = __builtin_amdgcn_rcpf(pAC * aB);
    c = fmaf(c, pAC, (eC - 1.0f) * aB) * r1;
    float eD = __expf(-a[3]);
    float eE = __expf(2.0f * c);
    float r2 = __builtin_amdgcn_rcpf((1.0f + eD) * (1.0f + eE));
    return (eE - 1.0f) * r2;
}

// ---------------------------------------------------------------------------
// Fused 5-layer LSTM via bf16 MFMA, hi/lo compensated.
//
// R4: R2's 8-wave/512-thread structure (best measured) with the in-place
// 20-slab buffer replaced by a 21-slab ROTATING buffer:
//   layer l stores h_l(t) at slot (t - l) mod 21.
// Per step, read slots {sw+1 (ih), sw-1 (hh)} and write slot {sw} are
// DISJOINT -> the read-vs-write hazard is gone and ONE barrier per step
// suffices (write -> next-step read). This removes 100 of the 200 barriers
// and the mid-step stall that serialized every wave on the slowest wave's
// MFMA+trans chain. The ih fragment is prefetched one step ahead (its slab
// is stable all pass), hiding the ~120 cy LDS latency behind the barrier.
// 21 slabs = 43008 B LDS -> 3 blocks/CU (24 waves; occupancy above 16 was
// measured near-flat, barriers were the cost).
// Math is bitwise-identical to R2 (same splits, same MFMA order per output).
//
// LDS h-slab layout (unchanged within a slab, e-major, natural unit pairs):
//   slab = [e 0..15][k 0..15] u32; u32 k holds units (2k, 2k+1);
//   k's bits[3:2] XORed with (e>>1)&3 (bank swizzle).
__global__ __launch_bounds__(512, 6)
void lstm5_mfma(const float* __restrict__ accel, const float* __restrict__ gyro,
                const float* __restrict__ aWih0, const float* __restrict__ aWihR,
                const float* __restrict__ aWhh,  const float* __restrict__ aBih,
                const float* __restrict__ aBhh,
                const float* __restrict__ gWih0, const float* __restrict__ gWihR,
                const float* __restrict__ gWhh,  const float* __restrict__ gBih,
                const float* __restrict__ gBhh,
                __bf16* __restrict__ Xhi, __bf16* __restrict__ Xlo) {
    const int tid  = threadIdx.x;
    const int w    = tid >> 6;        // wave 0..7
    const int lane = tid & 63;
    const int e    = lane & 15;       // batch col within group
    const int quad = lane >> 4;       // 0..3
    const int sensor = blockIdx.y;
    const int bbase  = blockIdx.x * 16;

    const float* xin  = sensor ? gyro  : accel;
    const float* Wih0 = sensor ? gWih0 : aWih0;
    const float* WihR = sensor ? gWihR : aWihR;
    const float* Whh  = sensor ? gWhh  : aWhh;
    const float* Bih  = sensor ? gBih  : aBih;
    const float* Bhh  = sensor ? gBhh  : aBhh;

    __shared__ __align__(16) __bf16 shi[NSLAB * 512];
    __shared__ __align__(16) __bf16 slo[NSLAB * 512];

    const int ug  = w * 4 + quad;        // this thread's hidden unit (0..31)
    const int swz = (e >> 1) & 3;

    // write index (bf16 units within a slab)
    const int widx = (e * 16 + ((w * 2 + (quad >> 1)) ^ (swz << 2))) * 2 + (quad & 1);
    // read base (bf16 units): 8 bf16 = units quad*8..quad*8+7 for col e
    const int rb_base = e * 32 + ((quad ^ swz) << 3);

    const int m_row = lane & 15;
    const int orow  = (m_row & 3) * 32 + (w * 4 + (m_row >> 2));

    bf16x8 wih_h, wih_l, whh_h, whh_l;
    f32x4  biasv;
    float  c0 = 0.f;

// A-frag natural column order: slot jj holds W[row][quad*8 + jj]
#define LOAD_FRAG(Wsrc, fh, fl)                               \
    {                                                         \
        const float* p_ = (Wsrc) + (orow) * 32 + quad * 8;    \
        _Pragma("unroll")                                     \
        for (int jj = 0; jj < 8; ++jj) {                      \
            __bf16 h_, l_;                                    \
            split_trunc(p_[jj], h_, l_);                      \
            (fh)[jj] = h_;  (fl)[jj] = l_;                    \
        }                                                     \
    }

#define LOAD_BIAS(l)                                                        \
    {                                                                       \
        _Pragma("unroll")                                                   \
        for (int r = 0; r < 4; ++r)                                         \
            biasv[r] = Bih[(l) * 128 + r * 32 + ug] + Bhh[(l) * 128 + r * 32 + ug]; \
    }

    // ================= layer 0 (ih is K=3, done in VALU) =================
    {
        LOAD_FRAG(Whh, whh_h, whh_l);
        LOAD_BIAS(0);
        float w0reg[4][3];
#pragma unroll
        for (int r = 0; r < 4; ++r)
#pragma unroll
            for (int k = 0; k < 3; ++k)
                w0reg[r][k] = Wih0[(r * 32 + ug) * 3 + k];
        const float* xrow = xin + (size_t)(bbase + e) * (T_STEPS * 3);

        int sw = 0;                       // write slot: (t - 0) mod 21
        for (int t = 0; t < T_STEPS; ++t) {
            float x0 = xrow[t * 3 + 0];
            float x1 = xrow[t * 3 + 1];
            float x2 = xrow[t * 3 + 2];
            f32x4 acc = biasv;
#pragma unroll
            for (int r = 0; r < 4; ++r)
                acc[r] = fmaf(w0reg[r][0], x0,
                         fmaf(w0reg[r][1], x1,
                         fmaf(w0reg[r][2], x2, acc[r])));
            if (t > 0) {
                int s_hh = sw - 1; if (s_hh < 0) s_hh += NSLAB;
                int rb = s_hh * 512 + rb_base;
                bf16x8 bh = *(const bf16x8*)&shi[rb];
                bf16x8 bl = *(const bf16x8*)&slo[rb];
                acc = __builtin_amdgcn_mfma_f32_16x16x32_bf16(whh_h, bh, acc, 0, 0, 0);
                acc = __builtin_amdgcn_mfma_f32_16x16x32_bf16(whh_h, bl, acc, 0, 0, 0);
                acc = __builtin_amdgcn_mfma_f32_16x16x32_bf16(whh_l, bh, acc, 0, 0, 0);
            }
            float h0 = lstm_act(acc, c0);
            __bf16 hh_, ll_;
            split_trunc(h0, hh_, ll_);
            shi[sw * 512 + widx] = hh_;
            slo[sw * 512 + widx] = ll_;
            __syncthreads();              // write -> next step's reads
            ++sw; if (sw >= NSLAB) sw -= NSLAB;
        }
    }

    // ================= layers 1..4 (both projections via MFMA) ===========
    for (int l = 1; l < 5; ++l) {
        const float* Wi = WihR + (l - 1) * 4096;
        const float* Wh = Whh + l * 4096;
        LOAD_FRAG(Wi, wih_h, wih_l);
        LOAD_FRAG(Wh, whh_h, whh_l);
        LOAD_BIAS(l);
        c0 = 0.f;

        int sw = NSLAB - l;               // write slot at t=0: (0 - l) mod 21
        // prologue: prefetch ih fragment for t=0 (slot sw+1 = h_{l-1}(0))
        bf16x8 ih_h, ih_l;
        {
            int s_ih = sw + 1; if (s_ih >= NSLAB) s_ih -= NSLAB;
            int rb = s_ih * 512 + rb_base;
            ih_h = *(const bf16x8*)&shi[rb];
            ih_l = *(const bf16x8*)&slo[rb];
        }

        for (int t = 0; t < T_STEPS; ++t) {
            // ih: x = h_{l-1}(t) (prefetched); bias rides in as C of first MFMA
            f32x4 acc;
            acc = __builtin_amdgcn_mfma_f32_16x16x32_bf16(wih_h, ih_h, biasv, 0, 0, 0);
            acc = __builtin_amdgcn_mfma_f32_16x16x32_bf16(wih_h, ih_l, acc, 0, 0, 0);
            acc = __builtin_amdgcn_mfma_f32_16x16x32_bf16(wih_l, ih_h, acc, 0, 0, 0);
            if (t > 0) {
                int s_hh = sw - 1; if (s_hh < 0) s_hh += NSLAB;
                int rb = s_hh * 512 + rb_base;
                bf16x8 bh = *(const bf16x8*)&shi[rb];
                bf16x8 bl = *(const bf16x8*)&slo[rb];
                acc = __builtin_amdgcn_mfma_f32_16x16x32_bf16(whh_h, bh, acc, 0, 0, 0);
                acc = __builtin_amdgcn_mfma_f32_16x16x32_bf16(whh_h, bl, acc, 0, 0, 0);
                acc = __builtin_amdgcn_mfma_f32_16x16x32_bf16(whh_l, bh, acc, 0, 0, 0);
            }
            float h0 = lstm_act(acc, c0);
            __bf16 hh_, ll_;
            split_trunc(h0, hh_, ll_);
            shi[sw * 512 + widx] = hh_;
            slo[sw * 512 + widx] = ll_;
            // prefetch next step's ih (slot sw+2; pass-stable slab, disjoint
            // from this step's write slot sw; junk at t=19, never used)
            {
                int s_pf = sw + 2; if (s_pf >= NSLAB) s_pf -= NSLAB;
                int rb = s_pf * 512 + rb_base;
                ih_h = *(const bf16x8*)&shi[rb];
                ih_l = *(const bf16x8*)&slo[rb];
            }
            __syncthreads();              // write -> next step's reads
            ++sw; if (sw >= NSLAB) sw -= NSLAB;
        }
    }
    __syncthreads();

    // ---- epilogue: copy layer-4 h slabs (slot (t+17)%21) to global ----
    {
        size_t base = ((size_t)(sensor * NGRP + blockIdx.x)) * (20 * 512);
        float4* dh = (float4*)(Xhi + base);
        float4* dl = (float4*)(Xlo + base);
        const float4* sh = (const float4*)shi;
        const float4* sl = (const float4*)slo;
        for (int i = tid; i < 1280; i += 512) {
            int tl   = i >> 6;                    // logical t (64 float4/slab)
            int phys = tl + 17; if (phys >= NSLAB) phys -= NSLAB;
            int off  = i & 63;
            dh[i] = sh[phys * 64 + off];
            dl[i] = sl[phys * 64 + off];
        }
    }
#undef LOAD_FRAG
#undef LOAD_BIAS
}

// ---------------------------------------------------------------------------
// fc1_w [128][1280] -> MFMA A-frag hi/lo arrays: [mt 0..7][ks 0..39][lane][8]
// Natural column order (matches natural-unit B layout). Unchanged from R2.
__global__ void w1_prep(const float* __restrict__ w1,
                        __bf16* __restrict__ w1ah, __bf16* __restrict__ w1al) {
    int t = blockIdx.x * blockDim.x + threadIdx.x;     // 8*40*64 = 20480
    if (t >= 20480) return;
    int lane = t & 63;
    int ks   = (t >> 6) % 40;
    int mt   = t / (64 * 40);
    int row  = mt * 16 + (lane & 15);
    int col0 = ks * 32 + (lane >> 4) * 8;
    const float* src = w1 + row * 1280 + col0;
#pragma unroll
    for (int j = 0; j < 8; ++j) {
        __bf16 h_, l_;
        split_trunc(src[j], h_, l_);
        w1ah[t * 8 + j] = h_;
        w1al[t * 8 + j] = l_;
    }
}

// ---------------------------------------------------------------------------
// Fused fc1+ReLU+fc2, K-split: block = 256 thr / 4 waves owns 16 batch cols;
// wave wv handles ks = wv*10 .. wv*10+9 (of 40) for ALL 8 m-tiles; C-partials
// reduced through LDS. Unchanged from R2.
__global__ __launch_bounds__(256, 4)
void fc_mfma(const __bf16* __restrict__ Xhi, const __bf16* __restrict__ Xlo,
             const __bf16* __restrict__ w1ah, const __bf16* __restrict__ w1al,
             const float* __restrict__ fc1_b, const float* __restrict__ fc2_w,
             const float* __restrict__ fc2_b, float* __restrict__ out) {
    const int tid  = threadIdx.x;
    const int wv   = tid >> 6;       // ks-quarter
    const int lane = tid & 63;
    const int e    = lane & 15;
    const int quad = lane >> 4;
    const int g    = blockIdx.x;     // batch group (16 cols)

    // match lstm5's physical layout: units quad*8..+7 for col e
    const int lnoff = e * 32 + ((quad ^ ((e >> 1) & 3)) << 3);

    __shared__ __align__(16) f32x4 sacc[4][8][64];   // 32 KB C-partials
    __shared__ float sred[4][16][5];

    f32x4 acc[8];
#pragma unroll
    for (int m = 0; m < 8; ++m) acc[m] = (f32x4){0.f, 0.f, 0.f, 0.f};

    for (int kk = 0; kk < 10; ++kk) {
        int ks = wv * 10 + kk;                 // 0..39
        int sensor = ks / 20, t = ks % 20;     // col = sensor*640 + t*32 + u
        size_t bb = ((size_t)(sensor * NGRP + g)) * (20 * 512) + t * 512 + lnoff;
        bf16x8 bh = *(const bf16x8*)(Xhi + bb);
        bf16x8 bl = *(const bf16x8*)(Xlo + bb);
#pragma unroll
        for (int m = 0; m < 8; ++m) {
            const __bf16* ap = w1ah + ((size_t)((m * 40 + ks) * 64 + lane)) * 8;
            const __bf16* al = w1al + ((size_t)((m * 40 + ks) * 64 + lane)) * 8;
            bf16x8 ah = *(const bf16x8*)ap;
            bf16x8 av = *(const bf16x8*)al;
            acc[m] = __builtin_amdgcn_mfma_f32_16x16x32_bf16(ah, bh, acc[m], 0, 0, 0);
            acc[m] = __builtin_amdgcn_mfma_f32_16x16x32_bf16(ah, bl, acc[m], 0, 0, 0);
            acc[m] = __builtin_amdgcn_mfma_f32_16x16x32_bf16(av, bh, acc[m], 0, 0, 0);
        }
    }
#pragma unroll
    for (int m = 0; m < 8; ++m) sacc[wv][m][lane] = acc[m];
    __syncthreads();

    // phase 2: wave wv reduces m-tiles {2wv, 2wv+1}: sum K-partials, bias,
    // ReLU, fc2 partial over its rows; butterfly over quad bits.
    float p[5] = {0.f, 0.f, 0.f, 0.f, 0.f};
#pragma unroll
    for (int mm = 0; mm < 2; ++mm) {
        int mt = wv * 2 + mm;
        f32x4 z = sacc[0][mt][lane];
#pragma unroll
        for (int k = 1; k < 4; ++k) {
            f32x4 zz = sacc[k][mt][lane];
#pragma unroll
            for (int r = 0; r < 4; ++r) z[r] += zz[r];
        }
#pragma unroll
        for (int r = 0; r < 4; ++r) {
            int row = mt * 16 + quad * 4 + r;      // C row = quad*4 + reg
            float v = fmaxf(z[r] + fc1_b[row], 0.f);
#pragma unroll
            for (int n = 0; n < 5; ++n) p[n] = fmaf(v, fc2_w[n * 128 + row], p[n]);
        }
    }
#pragma unroll
    for (int n = 0; n < 5; ++n) {
        p[n] += __shfl_xor(p[n], 16, 64);
        p[n] += __shfl_xor(p[n], 32, 64);
    }
    if (quad == 0) {
#pragma unroll
        for (int n = 0; n < 5; ++n) sred[wv][e][n] = p[n];
    }
    __syncthreads();
    if (tid < 80) {
        int col = tid / 5, n = tid - col * 5;
        out[(size_t)(g * 16 + col) * 5 + n] =
            sred[0][col][n] + sred[1][col][n] + sred[2][col][n] + sred[3][col][n] + fc2_b[n];
    }
}

// ---------------------------------------------------------------------------
extern "C" void kernel_launch(void* const* d_in, const int* in_sizes, int n_in,
                              void* d_out, int out_size, void* d_ws, size_t ws_size,
                              hipStream_t stream) {
    const float* accel  = (const float*)d_in[0];
    const float* gyro   = (const float*)d_in[1];
    const float* aWih0  = (const float*)d_in[2];
    const float* aWihR  = (const float*)d_in[3];
    const float* aWhh   = (const float*)d_in[4];
    const float* aBih   = (const float*)d_in[5];
    const float* aBhh   = (const float*)d_in[6];
    const float* gWih0  = (const float*)d_in[7];
    const float* gWihR  = (const float*)d_in[8];
    const float* gWhh   = (const float*)d_in[9];
    const float* gBih   = (const float*)d_in[10];
    const float* gBhh   = (const float*)d_in[11];
    const float* fc1_w  = (const float*)d_in[12];
    const float* fc1_b  = (const float*)d_in[13];
    const float* fc2_w  = (const float*)d_in[14];
    const float* fc2_b  = (const float*)d_in[15];
    float* out = (float*)d_out;

    const size_t XN = (size_t)2 * NGRP * 20 * 512;    // 20,971,520 bf16 each
    __bf16* Xhi  = (__bf16*)d_ws;
    __bf16* Xlo  = Xhi + XN;
    __bf16* W1ah = Xlo + XN;                          // 163,840 bf16 each
    __bf16* W1al = W1ah + 163840;

    hipLaunchKernelGGL(w1_prep, dim3(80), dim3(256), 0, stream, fc1_w, W1ah, W1al);

    hipLaunchKernelGGL(lstm5_mfma, dim3(NGRP, 2), dim3(512), 0, stream,
                       accel, gyro, aWih0, aWihR, aWhh, aBih, aBhh,
                       gWih0, gWihR, gWhh, gBih, gBhh, Xhi, Xlo);

    hipLaunchKernelGGL(fc_mfma, dim3(NGRP), dim3(256), 0, stream,
                       Xhi, Xlo, W1ah, W1al, fc1_b, fc2_w, fc2_b, out);
}

// Round 5
// 285.704 us; speedup vs baseline: 1.1098x; 1.0818x over previous
//
#include <hip/hip_runtime.h>
#include <math.h>

#define B_TOTAL 16384
#define T_STEPS 20
#define NGRP    1024            // B_TOTAL/16 batch groups per sensor

typedef __attribute__((ext_vector_type(8))) __bf16 bf16x8;
typedef __attribute__((ext_vector_type(4))) float f32x4;

#define LOG2E_F 1.4426950408889634f
#define K2_F    2.8853900817779268f   // 2*log2(e)

// ---------------------------------------------------------------------------
__device__ __forceinline__ float exp2_fast(float x) {
#if __has_builtin(__builtin_amdgcn_exp2f)
    return __builtin_amdgcn_exp2f(x);       // bare v_exp_f32 (2^x)
#else
    return __expf(x * 0.6931471805599453f); // fallback: exp(ln2*x)
#endif
}

__device__ __forceinline__ __bf16 bf16_bits(unsigned short s) {
    __bf16 r; __builtin_memcpy(&r, &s, 2); return r;
}
// Truncation-based Dekker split (unchanged numerics).
__device__ __forceinline__ void split_trunc(float x, __bf16& hi, __bf16& lo) {
    unsigned u = __float_as_uint(x);
    hi = bf16_bits((unsigned short)(u >> 16));
    float l = x - __uint_as_float(u & 0xFFFF0000u);
    lo = bf16_bits((unsigned short)(__float_as_uint(l) >> 16));
}

// Fused LSTM cell activation in the exp2 domain. Pre-activations a are
// PRE-SCALED: gates i,f,o by log2e, gate g by 2*log2e (folded into the
// bf16 weight/bias fragments at load time). Algebraically identical to
// the sigmoid/tanh form:
//   c' = [c*(1+A)(1+C) + (C-1)(1+B)] / [(1+A)(1+B)(1+C)]
//     A=2^-a0=e^-xi  B=2^-a1=e^-xf  C=2^a2=e^2xg
//   h  = (E-1) / ((1+D)(1+E))   D=2^-a3=e^-xo  E=2^(K2*c')=e^2c'
__device__ __forceinline__ float lstm_act2(f32x4 a, float& c) {
    float eA = exp2_fast(-a[0]);
    float eB = exp2_fast(-a[1]);
    float eC = exp2_fast(a[2]);
    float aA = 1.0f + eA, aB = 1.0f + eB, aC = 1.0f + eC;
    float pAC = aA * aC;
    float r1  = __builtin_amdgcn_rcpf(pAC * aB);
    c = fmaf(c, pAC, (eC - 1.0f) * aB) * r1;
    float eD = exp2_fast(-a[3]);
    float eE = exp2_fast(K2_F * c);
    float r2 = __builtin_amdgcn_rcpf((1.0f + eD) * (1.0f + eE));
    return (eE - 1.0f) * r2;
}

// ---------------------------------------------------------------------------
// Fused 5-layer LSTM via bf16 MFMA, hi/lo compensated.
//
// R5 = R2's 8-wave/512-thread/40KB structure (best measured: 4 blocks/CU,
// 32 waves/CU) with ONE barrier per step instead of two:
//   in-place slabs (slab t holds the current layer's h(t)), and the ih
//   fragment is REGISTER-PREFETCHED one step ahead. Step t accesses:
//     read slab t-1 (hh operand)  |  read slab t+1 (ih prefetch for t+1)
//     write slab t                -> all three disjoint -> no read/write
//   hazard within a step; the single barrier orders write(t) before the
//   next step's reads. Per layer entry, a prologue prefetch of slab 0
//   (h_{l-1}(0)) + one barrier closes the only remaining race.
// The MFMA-layer t-loop is FULLY UNROLLED: every ds_read/ds_write gets a
// compile-time slab offset (base VGPR + immediate), zero per-step address
// VALU. Weights/biases are prescaled into the exp2 domain at load time
// (saves 4 v_mul per activation; the SIMD issue port is the bottleneck).
//
// LDS h-slab layout (identical to R2): slab = [e 0..15][k 0..15] u32;
// u32 k holds units (2k,2k+1); k bits[3:2] XOR (e>>1)&3 bank swizzle.
__global__ __launch_bounds__(512, 8)
void lstm5_mfma(const float* __restrict__ accel, const float* __restrict__ gyro,
                const float* __restrict__ aWih0, const float* __restrict__ aWihR,
                const float* __restrict__ aWhh,  const float* __restrict__ aBih,
                const float* __restrict__ aBhh,
                const float* __restrict__ gWih0, const float* __restrict__ gWihR,
                const float* __restrict__ gWhh,  const float* __restrict__ gBih,
                const float* __restrict__ gBhh,
                __bf16* __restrict__ Xhi, __bf16* __restrict__ Xlo) {
    const int tid  = threadIdx.x;
    const int w    = tid >> 6;        // wave 0..7
    const int lane = tid & 63;
    const int e    = lane & 15;       // batch col within group
    const int quad = lane >> 4;       // 0..3
    const int sensor = blockIdx.y;
    const int bbase  = blockIdx.x * 16;

    const float* xin  = sensor ? gyro  : accel;
    const float* Wih0 = sensor ? gWih0 : aWih0;
    const float* WihR = sensor ? gWihR : aWihR;
    const float* Whh  = sensor ? gWhh  : aWhh;
    const float* Bih  = sensor ? gBih  : aBih;
    const float* Bhh  = sensor ? gBhh  : aBhh;

    __shared__ __align__(16) __bf16 shi[T_STEPS * 512];   // 20 KB
    __shared__ __align__(16) __bf16 slo[T_STEPS * 512];   // 20 KB -> 40960 total

    const int ug  = w * 4 + quad;        // this thread's hidden unit (0..31)
    const int swz = (e >> 1) & 3;

    // write index (bf16 units within a slab)
    const int widx = (e * 16 + ((w * 2 + (quad >> 1)) ^ (swz << 2))) * 2 + (quad & 1);
    // read base (bf16 units): 8 bf16 = units quad*8..quad*8+7 for col e
    const int rb_base = e * 32 + ((quad ^ swz) << 3);

    const int m_row = lane & 15;
    const int orow  = (m_row & 3) * 32 + (w * 4 + (m_row >> 2));
    // exp2-domain row scale: gate g (index 2) gets 2*log2e, others log2e
    const float wscale = ((m_row & 3) == 2) ? K2_F : LOG2E_F;

    bf16x8 wih_h, wih_l, whh_h, whh_l;
    bf16x8 ih_h, ih_l;                   // prefetched ih fragment
    f32x4  biasv;
    float  c0 = 0.f;

// A-frag natural column order, prescaled: slot jj = wscale*W[row][quad*8+jj]
#define LOAD_FRAG(Wsrc, fh, fl)                               \
    {                                                         \
        const float* p_ = (Wsrc) + (orow) * 32 + quad * 8;    \
        _Pragma("unroll")                                     \
        for (int jj = 0; jj < 8; ++jj) {                      \
            __bf16 h_, l_;                                    \
            split_trunc(p_[jj] * wscale, h_, l_);             \
            (fh)[jj] = h_;  (fl)[jj] = l_;                    \
        }                                                     \
    }

#define LOAD_BIAS(l)                                                        \
    {                                                                       \
        _Pragma("unroll")                                                   \
        for (int r = 0; r < 4; ++r) {                                       \
            float bs_ = (r == 2) ? K2_F : LOG2E_F;                          \
            biasv[r] = (Bih[(l) * 128 + r * 32 + ug] +                      \
                        Bhh[(l) * 128 + r * 32 + ug]) * bs_;                \
        }                                                                   \
    }

    // ================= layer 0 (ih is K=3, done in VALU) =================
    {
        LOAD_FRAG(Whh, whh_h, whh_l);
        LOAD_BIAS(0);
        float w0reg[4][3];
#pragma unroll
        for (int r = 0; r < 4; ++r) {
            float bs_ = (r == 2) ? K2_F : LOG2E_F;
#pragma unroll
            for (int k = 0; k < 3; ++k)
                w0reg[r][k] = Wih0[(r * 32 + ug) * 3 + k] * bs_;
        }
        const float* xrow = xin + (size_t)(bbase + e) * (T_STEPS * 3);

        for (int t = 0; t < T_STEPS; ++t) {
            float x0 = xrow[t * 3 + 0];
            float x1 = xrow[t * 3 + 1];
            float x2 = xrow[t * 3 + 2];
            f32x4 acc = biasv;
#pragma unroll
            for (int r = 0; r < 4; ++r)
                acc[r] = fmaf(w0reg[r][0], x0,
                         fmaf(w0reg[r][1], x1,
                         fmaf(w0reg[r][2], x2, acc[r])));
            if (t > 0) {
                int rb = (t - 1) * 512 + rb_base;
                bf16x8 bh = *(const bf16x8*)&shi[rb];
                bf16x8 bl = *(const bf16x8*)&slo[rb];
                acc = __builtin_amdgcn_mfma_f32_16x16x32_bf16(whh_h, bh, acc, 0, 0, 0);
                acc = __builtin_amdgcn_mfma_f32_16x16x32_bf16(whh_h, bl, acc, 0, 0, 0);
                acc = __builtin_amdgcn_mfma_f32_16x16x32_bf16(whh_l, bh, acc, 0, 0, 0);
            }
            float h0 = lstm_act2(acc, c0);
            __bf16 hh_, ll_;
            split_trunc(h0, hh_, ll_);
            shi[t * 512 + widx] = hh_;
            slo[t * 512 + widx] = ll_;
            __syncthreads();              // write(t) -> next step's hh read
        }
    }

// -------- fully-unrolled MFMA-layer step (t is a compile-time constant) ----
#define STEP_L(t)                                                           \
    {                                                                       \
        bf16x8 bh, bl, pf_h, pf_l;                                          \
        if ((t) > 0) {                                                      \
            bh = *(const bf16x8*)&shi[((t) - 1) * 512 + rb_base];           \
            bl = *(const bf16x8*)&slo[((t) - 1) * 512 + rb_base];           \
        }                                                                   \
        if ((t) < T_STEPS - 1) {      /* prefetch next step's ih */         \
            pf_h = *(const bf16x8*)&shi[((t) + 1) * 512 + rb_base];         \
            pf_l = *(const bf16x8*)&slo[((t) + 1) * 512 + rb_base];         \
        }                                                                   \
        f32x4 acc;                                                          \
        acc = __builtin_amdgcn_mfma_f32_16x16x32_bf16(wih_h, ih_h, biasv, 0, 0, 0); \
        acc = __builtin_amdgcn_mfma_f32_16x16x32_bf16(wih_h, ih_l, acc, 0, 0, 0);   \
        acc = __builtin_amdgcn_mfma_f32_16x16x32_bf16(wih_l, ih_h, acc, 0, 0, 0);   \
        if ((t) > 0) {                                                      \
            acc = __builtin_amdgcn_mfma_f32_16x16x32_bf16(whh_h, bh, acc, 0, 0, 0); \
            acc = __builtin_amdgcn_mfma_f32_16x16x32_bf16(whh_h, bl, acc, 0, 0, 0); \
            acc = __builtin_amdgcn_mfma_f32_16x16x32_bf16(whh_l, bh, acc, 0, 0, 0); \
        }                                                                   \
        float h0 = lstm_act2(acc, c0);                                      \
        __bf16 hh_, ll_;                                                    \
        split_trunc(h0, hh_, ll_);                                          \
        shi[(t) * 512 + widx] = hh_;                                        \
        slo[(t) * 512 + widx] = ll_;                                        \
        if ((t) < T_STEPS - 1) { ih_h = pf_h; ih_l = pf_l; }                \
        __syncthreads();              /* write(t) -> next step's reads */   \
    }

    // ================= layers 1..4 (both projections via MFMA) ===========
    for (int l = 1; l < 5; ++l) {
        const float* Wi = WihR + (l - 1) * 4096;
        const float* Wh = Whh + l * 4096;
        LOAD_FRAG(Wi, wih_h, wih_l);
        LOAD_FRAG(Wh, whh_h, whh_l);
        LOAD_BIAS(l);
        c0 = 0.f;

        // prologue: prefetch ih(0) = h_{l-1}(0) from slab 0 (stable), then
        // barrier so no wave's t=0 write to slab 0 races another's read.
        ih_h = *(const bf16x8*)&shi[rb_base];
        ih_l = *(const bf16x8*)&slo[rb_base];
        __syncthreads();

#pragma unroll
        for (int t = 0; t < T_STEPS; ++t) STEP_L(t);
    }
    __syncthreads();

    // ---- epilogue: raw copy of (physical) frag-layout hi/lo to global ----
    {
        size_t base = ((size_t)(sensor * NGRP + blockIdx.x)) * (20 * 512);
        float4* dh = (float4*)(Xhi + base);
        float4* dl = (float4*)(Xlo + base);
        const float4* sh = (const float4*)shi;
        const float4* sl = (const float4*)slo;
        for (int i = tid; i < 1280; i += 512) { dh[i] = sh[i]; dl[i] = sl[i]; }
    }
#undef LOAD_FRAG
#undef LOAD_BIAS
#undef STEP_L
}

// ---------------------------------------------------------------------------
// fc1_w [128][1280] -> MFMA A-frag hi/lo arrays: [mt 0..7][ks 0..39][lane][8]
// Natural column order (matches natural-unit B layout). Unchanged from R2.
__global__ void w1_prep(const float* __restrict__ w1,
                        __bf16* __restrict__ w1ah, __bf16* __restrict__ w1al) {
    int t = blockIdx.x * blockDim.x + threadIdx.x;     // 8*40*64 = 20480
    if (t >= 20480) return;
    int lane = t & 63;
    int ks   = (t >> 6) % 40;
    int mt   = t / (64 * 40);
    int row  = mt * 16 + (lane & 15);
    int col0 = ks * 32 + (lane >> 4) * 8;
    const float* src = w1 + row * 1280 + col0;
#pragma unroll
    for (int j = 0; j < 8; ++j) {
        __bf16 h_, l_;
        split_trunc(src[j], h_, l_);
        w1ah[t * 8 + j] = h_;
        w1al[t * 8 + j] = l_;
    }
}

// ---------------------------------------------------------------------------
// Fused fc1+ReLU+fc2, K-split: block = 256 thr / 4 waves owns 16 batch cols;
// wave wv handles ks = wv*10 .. wv*10+9 (of 40) for ALL 8 m-tiles; C-partials
// reduced through LDS. Unchanged from R2.
__global__ __launch_bounds__(256, 4)
void fc_mfma(const __bf16* __restrict__ Xhi, const __bf16* __restrict__ Xlo,
             const __bf16* __restrict__ w1ah, const __bf16* __restrict__ w1al,
             const float* __restrict__ fc1_b, const float* __restrict__ fc2_w,
             const float* __restrict__ fc2_b, float* __restrict__ out) {
    const int tid  = threadIdx.x;
    const int wv   = tid >> 6;       // ks-quarter
    const int lane = tid & 63;
    const int e    = lane & 15;
    const int quad = lane >> 4;
    const int g    = blockIdx.x;     // batch group (16 cols)

    // match lstm5's physical layout: units quad*8..+7 for col e
    const int lnoff = e * 32 + ((quad ^ ((e >> 1) & 3)) << 3);

    __shared__ __align__(16) f32x4 sacc[4][8][64];   // 32 KB C-partials
    __shared__ float sred[4][16][5];

    f32x4 acc[8];
#pragma unroll
    for (int m = 0; m < 8; ++m) acc[m] = (f32x4){0.f, 0.f, 0.f, 0.f};

    for (int kk = 0; kk < 10; ++kk) {
        int ks = wv * 10 + kk;                 // 0..39
        int sensor = ks / 20, t = ks % 20;     // col = sensor*640 + t*32 + u
        size_t bb = ((size_t)(sensor * NGRP + g)) * (20 * 512) + t * 512 + lnoff;
        bf16x8 bh = *(const bf16x8*)(Xhi + bb);
        bf16x8 bl = *(const bf16x8*)(Xlo + bb);
#pragma unroll
        for (int m = 0; m < 8; ++m) {
            const __bf16* ap = w1ah + ((size_t)((m * 40 + ks) * 64 + lane)) * 8;
            const __bf16* al = w1al + ((size_t)((m * 40 + ks) * 64 + lane)) * 8;
            bf16x8 ah = *(const bf16x8*)ap;
            bf16x8 av = *(const bf16x8*)al;
            acc[m] = __builtin_amdgcn_mfma_f32_16x16x32_bf16(ah, bh, acc[m], 0, 0, 0);
            acc[m] = __builtin_amdgcn_mfma_f32_16x16x32_bf16(ah, bl, acc[m], 0, 0, 0);
            acc[m] = __builtin_amdgcn_mfma_f32_16x16x32_bf16(av, bh, acc[m], 0, 0, 0);
        }
    }
#pragma unroll
    for (int m = 0; m < 8; ++m) sacc[wv][m][lane] = acc[m];
    __syncthreads();

    // phase 2: wave wv reduces m-tiles {2wv, 2wv+1}: sum K-partials, bias,
    // ReLU, fc2 partial over its rows; butterfly over quad bits.
    float p[5] = {0.f, 0.f, 0.f, 0.f, 0.f};
#pragma unroll
    for (int mm = 0; mm < 2; ++mm) {
        int mt = wv * 2 + mm;
        f32x4 z = sacc[0][mt][lane];
#pragma unroll
        for (int k = 1; k < 4; ++k) {
            f32x4 zz = sacc[k][mt][lane];
#pragma unroll
            for (int r = 0; r < 4; ++r) z[r] += zz[r];
        }
#pragma unroll
        for (int r = 0; r < 4; ++r) {
            int row = mt * 16 + quad * 4 + r;      // C row = quad*4 + reg
            float v = fmaxf(z[r] + fc1_b[row], 0.f);
#pragma unroll
            for (int n = 0; n < 5; ++n) p[n] = fmaf(v, fc2_w[n * 128 + row], p[n]);
        }
    }
#pragma unroll
    for (int n = 0; n < 5; ++n) {
        p[n] += __shfl_xor(p[n], 16, 64);
        p[n] += __shfl_xor(p[n], 32, 64);
    }
    if (quad == 0) {
#pragma unroll
        for (int n = 0; n < 5; ++n) sred[wv][e][n] = p[n];
    }
    __syncthreads();
    if (tid < 80) {
        int col = tid / 5, n = tid - col * 5;
        out[(size_t)(g * 16 + col) * 5 + n] =
            sred[0][col][n] + sred[1][col][n] + sred[2][col][n] + sred[3][col][n] + fc2_b[n];
    }
}

// ---------------------------------------------------------------------------
extern "C" void kernel_launch(void* const* d_in, const int* in_sizes, int n_in,
                              void* d_out, int out_size, void* d_ws, size_t ws_size,
                              hipStream_t stream) {
    const float* accel  = (const float*)d_in[0];
    const float* gyro   = (const float*)d_in[1];
    const float* aWih0  = (const float*)d_in[2];
    const float* aWihR  = (const float*)d_in[3];
    const float* aWhh   = (const float*)d_in[4];
    const float* aBih   = (const float*)d_in[5];
    const float* aBhh   = (const float*)d_in[6];
    const float* gWih0  = (const float*)d_in[7];
    const float* gWihR  = (const float*)d_in[8];
    const float* gWhh   = (const float*)d_in[9];
    const float* gBih   = (const float*)d_in[10];
    const float* gBhh   = (const float*)d_in[11];
    const float* fc1_w  = (const float*)d_in[12];
    const float* fc1_b  = (const float*)d_in[13];
    const float* fc2_w  = (const float*)d_in[14];
    const float* fc2_b  = (const float*)d_in[15];
    float* out = (float*)d_out;

    const size_t XN = (size_t)2 * NGRP * 20 * 512;    // 20,971,520 bf16 each
    __bf16* Xhi  = (__bf16*)d_ws;
    __bf16* Xlo  = Xhi + XN;
    __bf16* W1ah = Xlo + XN;                          // 163,840 bf16 each
    __bf16* W1al = W1ah + 163840;

    hipLaunchKernelGGL(w1_prep, dim3(80), dim3(256), 0, stream, fc1_w, W1ah, W1al);

    hipLaunchKernelGGL(lstm5_mfma, dim3(NGRP, 2), dim3(512), 0, stream,
                       accel, gyro, aWih0, aWihR, aWhh, aBih, aBhh,
                       gWih0, gWihR, gWhh, gBih, gBhh, Xhi, Xlo);

    hipLaunchKernelGGL(fc_mfma, dim3(NGRP), dim3(256), 0, stream,
                       Xhi, Xlo, W1ah, W1al, fc1_b, fc2_w, fc2_b, out);
}